// Round 4
// baseline (491.295 us; speedup 1.0000x reference)
//
#include <hip/hip_runtime.h>

#define NPGL 256     // nodes per graph
#define EPGL 2048    // edges per graph
#define KKEEP 128
#define NTH 1024
#define WS_STRIDE 1344   // floats per (graph,half) exchange slot

// float offset of float4-chunk c (0..7) of row n in the 32-wide swizzled tile
__device__ __forceinline__ int swz8(int n, int c) {
  return (n << 5) + (((c ^ n ^ (n >> 3)) & 7) << 2);
}

__device__ __forceinline__ void pair_sync(int* flags, int bid, int s) {
  __syncthreads();
  if (threadIdx.x == 0) {
    __threadfence();
    __hip_atomic_store(&flags[bid * 4 + s], 1, __ATOMIC_RELEASE, __HIP_MEMORY_SCOPE_AGENT);
    while (__hip_atomic_load(&flags[(bid ^ 1) * 4 + s], __ATOMIC_ACQUIRE,
                             __HIP_MEMORY_SCOPE_AGENT) == 0) {
      __builtin_amdgcn_s_sleep(2);
    }
  }
  __syncthreads();
  __threadfence();   // invalidate caches before reading partner data
}

__global__ void __launch_bounds__(NTH, 8)
asap_fused(const float* __restrict__ x, const int* __restrict__ ei,
           const float* __restrict__ W1, const float* __restrict__ b1,
           const float* __restrict__ linW, const float* __restrict__ linb,
           const float* __restrict__ attW, const float* __restrict__ attb,
           const float* __restrict__ le1W, const float* __restrict__ le1b,
           const float* __restrict__ le2W,
           const float* __restrict__ le3W, const float* __restrict__ le3b,
           const float* __restrict__ W2, const float* __restrict__ b2,
           float* __restrict__ out, int* __restrict__ flags,
           float* __restrict__ dat, int Etot)
{
  const int bid = blockIdx.x;
  const int g   = bid >> 1;        // graph
  const int fh  = bid & 1;         // feature half
  const int F0  = fh << 5;         // feature base (0 or 32)
  const int tid = threadIdx.x;

  __shared__ __align__(16) float buf[NPGL * 32];   // 32KB: x-half -> h-half -> h1 -> xnew
  __shared__ __align__(16) float esc[EPGL];        // 8KB: exp scores / ph11 partials
  __shared__ unsigned short csrc[EPGL];            // 4KB CSR src (by dst)
  __shared__ int rowst[NPGL + 1];
  __shared__ int cnt[NPGL];
  __shared__ float dinv_[NPGL];                    // conv1 norm -> c3
  __shared__ float sA[NPGL], sB[NPGL];             // att partial -> a, b
  __shared__ float eself[NPGL];
  __shared__ float rsf[NPGL];                      // recip softmax sum -> fitness
  __shared__ float u_[32];
  __shared__ float wsum[64];
  __shared__ int scanw[4];
  __shared__ float c0s;
  __shared__ unsigned long long Imask[NPGL * 4];   // 8KB
  __shared__ unsigned long long Rmask[KKEEP * 4];  // 4KB
  __shared__ unsigned long long conn[KKEEP * 2];   // 1KB
  __shared__ int kept[KKEEP];
  __shared__ float d2A[KKEEP];
  __shared__ float cA[KKEEP];

  float* const datm = dat + (size_t)bid * WS_STRIDE;
  const float* const datp = dat + (size_t)(bid ^ 1) * WS_STRIDE;

  const int ebase = g * EPGL;
  const int nbase = g * NPGL;

  // ---------------- Phase 0: CSR build (by dst) ----------------
  if (tid < NPGL) cnt[tid] = 0;
  __syncthreads();

  int es[2], ed[2];
#pragma unroll
  for (int i = 0; i < 2; ++i) {
    const int e = tid + i * NTH;
    es[i] = ei[ebase + e] - nbase;
    ed[i] = ei[Etot + ebase + e] - nbase;
    atomicAdd(&cnt[ed[i]], 1);
  }
  __syncthreads();

  int vscan = 0;
  if (tid < NPGL) {                 // wave-level inclusive scan over 256 counts
    vscan = cnt[tid];
#pragma unroll
    for (int off = 1; off < 64; off <<= 1) {
      const int up = __shfl_up(vscan, off, 64);
      if ((tid & 63) >= off) vscan += up;
    }
    if ((tid & 63) == 63) scanw[tid >> 6] = vscan;
  }
  __syncthreads();
  if (tid < NPGL) {
    int add = 0;
    const int w = tid >> 6;
    for (int ww = 0; ww < w; ++ww) add += scanw[ww];
    const int incl = vscan + add;
    rowst[tid + 1] = incl;
    cnt[tid] = incl - cnt[tid];     // exclusive scan = scatter cursor
    if (tid == 0) rowst[0] = 0;
  }
  __syncthreads();

#pragma unroll
  for (int i = 0; i < 2; ++i) {
    const int p = atomicAdd(&cnt[ed[i]], 1);
    csrc[p] = (unsigned short)es[i];
  }
  if (tid < NPGL) {
    const int len = rowst[tid + 1] - rowst[tid];
    dinv_[tid] = rsqrtf((float)len + 1.0f);       // conv1: +1 self loop
  }
  if (tid < 32) {                  // u_local = (lin_W @ attW[:64])[F0+tid]
    float a = 0.f;
    for (int f = 0; f < 64; ++f) a += linW[(F0 + tid) * 64 + f] * attW[f];
    u_[tid] = a;
  }
  if (tid == 0) {
    float a = 0.f;
    for (int f = 0; f < 64; ++f) a += linb[f] * attW[f];
    c0s = a + attb[0];
  }
  __syncthreads();

  // ---------------- Phase 1: h[:,F0:F0+32] = x @ W1[:,F0:F0+32] ----------------
  {
    const int wv = tid >> 6;
    const int colg = wv >> 2;                  // 0..3 wave-uniform (8 cols)
    const int r = ((wv & 3) << 6) | (tid & 63);
    float4 acc0 = make_float4(0.f, 0.f, 0.f, 0.f);
    float4 acc1 = make_float4(0.f, 0.f, 0.f, 0.f);
#pragma unroll
    for (int p = 0; p < 2; ++p) {
      // stage k-half of x (swizzled)
#pragma unroll
      for (int ii = 0; ii < 2; ++ii) {
        const int u = tid + ii * NTH;
        const int n = u >> 3, c = u & 7;
        *(float4*)&buf[swz8(n, c)] =
            *(const float4*)&x[(size_t)(nbase + n) * 64 + p * 32 + c * 4];
      }
      __syncthreads();
      const float* __restrict__ Wp = W1 + (p * 32) * 64 + F0 + colg * 8; // scalar
#pragma unroll
      for (int c = 0; c < 8; ++c) {
        const float4 xa = *(const float4*)&buf[swz8(r, c)];
        const float* xf = (const float*)&xa;
#pragma unroll
        for (int q = 0; q < 4; ++q) {
          const int kk = c * 4 + q;
          const float xv = xf[q];
          const float4 w0 = *(const float4*)(Wp + kk * 64);
          const float4 w1 = *(const float4*)(Wp + kk * 64 + 4);
          acc0.x += xv * w0.x; acc0.y += xv * w0.y;
          acc0.z += xv * w0.z; acc0.w += xv * w0.w;
          acc1.x += xv * w1.x; acc1.y += xv * w1.y;
          acc1.z += xv * w1.z; acc1.w += xv * w1.w;
        }
      }
      __syncthreads();
    }
    *(float4*)&buf[swz8(r, colg * 2)] = acc0;
    *(float4*)&buf[swz8(r, colg * 2 + 1)] = acc1;
  }
  __syncthreads();

  // ---------------- Phase 2: h1 = relu(GCN agg) (in-place, 2 chunks/lane) ----------------
  {
    const int d = tid >> 2, hh = tid & 3;      // chunks hh, hh+4
    const float dd = dinv_[d];
    const float sc_ = dd * dd;
    const float4 bv0 = *(const float4*)&b1[F0 + hh * 4];
    const float4 bv1 = *(const float4*)&b1[F0 + (hh + 4) * 4];
    float4 a0, a1;
    {
      const float4 h0 = *(const float4*)&buf[swz8(d, hh)];
      const float4 h1v = *(const float4*)&buf[swz8(d, hh + 4)];
      a0.x = h0.x * sc_ + bv0.x; a0.y = h0.y * sc_ + bv0.y;
      a0.z = h0.z * sc_ + bv0.z; a0.w = h0.w * sc_ + bv0.w;
      a1.x = h1v.x * sc_ + bv1.x; a1.y = h1v.y * sc_ + bv1.y;
      a1.z = h1v.z * sc_ + bv1.z; a1.w = h1v.w * sc_ + bv1.w;
    }
    const int s0 = rowst[d], s1 = rowst[d + 1];
    int it = s0;
    for (; it + 2 <= s1; it += 2) {
      const int sa_ = csrc[it], sb_ = csrc[it + 1];
      const float ca_ = dinv_[sa_] * dd, cb_ = dinv_[sb_] * dd;
      const float4 ha0 = *(const float4*)&buf[swz8(sa_, hh)];
      const float4 ha1 = *(const float4*)&buf[swz8(sa_, hh + 4)];
      const float4 hb0 = *(const float4*)&buf[swz8(sb_, hh)];
      const float4 hb1 = *(const float4*)&buf[swz8(sb_, hh + 4)];
      a0.x += ca_ * ha0.x + cb_ * hb0.x; a0.y += ca_ * ha0.y + cb_ * hb0.y;
      a0.z += ca_ * ha0.z + cb_ * hb0.z; a0.w += ca_ * ha0.w + cb_ * hb0.w;
      a1.x += ca_ * ha1.x + cb_ * hb1.x; a1.y += ca_ * ha1.y + cb_ * hb1.y;
      a1.z += ca_ * ha1.z + cb_ * hb1.z; a1.w += ca_ * ha1.w + cb_ * hb1.w;
    }
    if (it < s1) {
      const int s = csrc[it];
      const float cf = dinv_[s] * dd;
      const float4 h0 = *(const float4*)&buf[swz8(s, hh)];
      const float4 h1v = *(const float4*)&buf[swz8(s, hh + 4)];
      a0.x += cf * h0.x; a0.y += cf * h0.y; a0.z += cf * h0.z; a0.w += cf * h0.w;
      a1.x += cf * h1v.x; a1.y += cf * h1v.y; a1.z += cf * h1v.z; a1.w += cf * h1v.w;
    }
    a0.x = fmaxf(a0.x, 0.f); a0.y = fmaxf(a0.y, 0.f);
    a0.z = fmaxf(a0.z, 0.f); a0.w = fmaxf(a0.w, 0.f);
    a1.x = fmaxf(a1.x, 0.f); a1.y = fmaxf(a1.y, 0.f);
    a1.z = fmaxf(a1.z, 0.f); a1.w = fmaxf(a1.w, 0.f);
    __syncthreads();
    *(float4*)&buf[swz8(d, hh)] = a0;
    *(float4*)&buf[swz8(d, hh + 4)] = a1;
  }
  __syncthreads();

  // ---------------- Phase 3: partial sA (segment-max dot u), partial sB ----------------
  {
    const int d = tid >> 2, hh = tid & 3;
    float4 m0 = *(const float4*)&buf[swz8(d, hh)];
    float4 m1 = *(const float4*)&buf[swz8(d, hh + 4)];
    const float4 aw0 = *(const float4*)&attW[64 + F0 + hh * 4];
    const float4 aw1 = *(const float4*)&attW[64 + F0 + (hh + 4) * 4];
    float sBp = m0.x * aw0.x + m0.y * aw0.y + m0.z * aw0.z + m0.w * aw0.w
              + m1.x * aw1.x + m1.y * aw1.y + m1.z * aw1.z + m1.w * aw1.w;
    const int s0 = rowst[d], s1 = rowst[d + 1];
    for (int it = s0; it < s1; ++it) {
      const int s = csrc[it];
      const float4 h0 = *(const float4*)&buf[swz8(s, hh)];
      const float4 h1v = *(const float4*)&buf[swz8(s, hh + 4)];
      m0.x = fmaxf(m0.x, h0.x); m0.y = fmaxf(m0.y, h0.y);
      m0.z = fmaxf(m0.z, h0.z); m0.w = fmaxf(m0.w, h0.w);
      m1.x = fmaxf(m1.x, h1v.x); m1.y = fmaxf(m1.y, h1v.y);
      m1.z = fmaxf(m1.z, h1v.z); m1.w = fmaxf(m1.w, h1v.w);
    }
    const float* u0 = &u_[hh * 4];
    const float* u1 = &u_[(hh + 4) * 4];
    float sAp = m0.x * u0[0] + m0.y * u0[1] + m0.z * u0[2] + m0.w * u0[3]
              + m1.x * u1[0] + m1.y * u1[1] + m1.z * u1[2] + m1.w * u1[3];
    sAp += __shfl_xor(sAp, 1); sAp += __shfl_xor(sAp, 2);
    sBp += __shfl_xor(sBp, 1); sBp += __shfl_xor(sBp, 2);
    if (hh == 0) { sA[d] = sAp; sB[d] = sBp; }
  }
  __syncthreads();
  // exchange #1
  if (tid < NPGL) { datm[tid] = sA[tid]; datm[256 + tid] = sB[tid]; }
  pair_sync(flags, bid, 0);
  if (tid < NPGL) {
    const float oa = sA[tid], pa = datp[tid];
    const float ob = sB[tid], pb = datp[256 + tid];
    const float la = fh ? pa : oa, ha = fh ? oa : pa;   // canonical half0+half1
    const float lb = fh ? pb : ob, hb = fh ? ob : pb;
    sA[tid] = (la + ha) + c0s;
    sB[tid] = lb + hb;
  }
  __syncthreads();

  // ---------------- Phase 4: per-target softmax (4 lanes/dst) ----------------
  {
    const int d = tid >> 2, q = tid & 3;
    const float sa = sA[d];
    const int s0 = rowst[d], s1 = rowst[d + 1];
    float scS = sa + sB[d];
    scS = scS >= 0.f ? scS : 0.2f * scS;
    float mxv = scS;
    for (int it = s0 + q; it < s1; it += 4) {
      float sc = sa + sB[csrc[it]];
      sc = sc >= 0.f ? sc : 0.2f * sc;
      mxv = fmaxf(mxv, sc);
    }
    mxv = fmaxf(mxv, __shfl_xor(mxv, 1));
    mxv = fmaxf(mxv, __shfl_xor(mxv, 2));
    float sum = 0.f;
    for (int it = s0 + q; it < s1; it += 4) {
      float sc = sa + sB[csrc[it]];
      sc = sc >= 0.f ? sc : 0.2f * sc;
      const float e = __expf(sc - mxv);
      esc[it] = e;
      sum += e;
    }
    sum += __shfl_xor(sum, 1); sum += __shfl_xor(sum, 2);
    const float esf = __expf(scS - mxv);
    if (q == 0) {
      eself[d] = esf;
      rsf[d] = 1.0f / (esf + sum + 1e-16f);
    }
  }
  __syncthreads();

  // ---------------- Phase 5: xnew = segsum(score * h1) (in-place) ----------------
  {
    const int d = tid >> 2, hh = tid & 3;
    const float esf = eself[d];
    float4 a0, a1;
    {
      const float4 h0 = *(const float4*)&buf[swz8(d, hh)];
      const float4 h1v = *(const float4*)&buf[swz8(d, hh + 4)];
      a0.x = esf * h0.x; a0.y = esf * h0.y; a0.z = esf * h0.z; a0.w = esf * h0.w;
      a1.x = esf * h1v.x; a1.y = esf * h1v.y; a1.z = esf * h1v.z; a1.w = esf * h1v.w;
    }
    const int s0 = rowst[d], s1 = rowst[d + 1];
    int it = s0;
    for (; it + 2 <= s1; it += 2) {
      const int sa_ = csrc[it], sb_ = csrc[it + 1];
      const float ea = esc[it], eb = esc[it + 1];
      const float4 ha0 = *(const float4*)&buf[swz8(sa_, hh)];
      const float4 ha1 = *(const float4*)&buf[swz8(sa_, hh + 4)];
      const float4 hb0 = *(const float4*)&buf[swz8(sb_, hh)];
      const float4 hb1 = *(const float4*)&buf[swz8(sb_, hh + 4)];
      a0.x += ea * ha0.x + eb * hb0.x; a0.y += ea * ha0.y + eb * hb0.y;
      a0.z += ea * ha0.z + eb * hb0.z; a0.w += ea * ha0.w + eb * hb0.w;
      a1.x += ea * ha1.x + eb * hb1.x; a1.y += ea * ha1.y + eb * hb1.y;
      a1.z += ea * ha1.z + eb * hb1.z; a1.w += ea * ha1.w + eb * hb1.w;
    }
    if (it < s1) {
      const int s = csrc[it];
      const float e = esc[it];
      const float4 h0 = *(const float4*)&buf[swz8(s, hh)];
      const float4 h1v = *(const float4*)&buf[swz8(s, hh + 4)];
      a0.x += e * h0.x; a0.y += e * h0.y; a0.z += e * h0.z; a0.w += e * h0.w;
      a1.x += e * h1v.x; a1.y += e * h1v.y; a1.z += e * h1v.z; a1.w += e * h1v.w;
    }
    const float r = rsf[d];
    a0.x *= r; a0.y *= r; a0.z *= r; a0.w *= r;
    a1.x *= r; a1.y *= r; a1.z *= r; a1.w *= r;
    __syncthreads();
    *(float4*)&buf[swz8(d, hh)] = a0;
    *(float4*)&buf[swz8(d, hh + 4)] = a1;
  }
  __syncthreads();

  // ---------------- Phase 6: LEConv partial dots, exchange, fitness ----------------
  {
    const int n = tid >> 2, q = tid & 3;
    float av = 0.f, bv = 0.f, cv = 0.f;
#pragma unroll
    for (int j = 0; j < 2; ++j) {
      const int c = q + 4 * j;
      const float4 v = *(const float4*)&buf[swz8(n, c)];
      const int k = F0 + c * 4;
      av += v.x * le1W[k] + v.y * le1W[k + 1] + v.z * le1W[k + 2] + v.w * le1W[k + 3];
      bv += v.x * le2W[k] + v.y * le2W[k + 1] + v.z * le2W[k + 2] + v.w * le2W[k + 3];
      cv += v.x * le3W[k] + v.y * le3W[k + 1] + v.z * le3W[k + 2] + v.w * le3W[k + 3];
    }
    av += __shfl_xor(av, 1); av += __shfl_xor(av, 2);
    bv += __shfl_xor(bv, 1); bv += __shfl_xor(bv, 2);
    cv += __shfl_xor(cv, 1); cv += __shfl_xor(cv, 2);
    if (q == 0) { sA[n] = av; sB[n] = bv; dinv_[n] = cv; }
  }
  __syncthreads();
  // exchange #2
  if (tid < NPGL) {
    datm[512 + tid] = sA[tid];
    datm[768 + tid] = sB[tid];
    datm[1024 + tid] = dinv_[tid];
  }
  pair_sync(flags, bid, 1);
  if (tid < NPGL) {
    const float oa = sA[tid], pa = datp[512 + tid];
    const float ob = sB[tid], pb = datp[768 + tid];
    const float oc = dinv_[tid], pc = datp[1024 + tid];
    const float la = fh ? pa : oa, ha = fh ? oa : pa;
    const float lb = fh ? pb : ob, hb = fh ? ob : pb;
    const float lc = fh ? pc : oc, hc = fh ? oc : pc;
    sA[tid] = (la + ha) + le1b[0];
    sB[tid] = lb + hb;
    dinv_[tid] = (lc + hc) + le3b[0];
  }
  __syncthreads();
  {
    // fitness: f64 edge-sum (exact -> order-independent across the pair)
    const int d = tid >> 2, q = tid & 3;
    const int s0 = rowst[d], s1 = rowst[d + 1];
    double fp = 0.0;
    for (int it = s0 + q; it < s1; it += 4) fp += (double)sA[csrc[it]];
    fp += __shfl_xor(fp, 1); fp += __shfl_xor(fp, 2);
    if (q == 0) {
      const float f = (float)((double)sA[d] + fp)
                      - (float)(s1 - s0 + 1) * sB[d] + dinv_[d];
      float sg;
      if (f >= 0.f) sg = 1.f / (1.f + expf(-f));
      else { const float t = expf(f); sg = t / (1.f + t); }
      rsf[d] = sg;                                 // fitness
    }
  }
  __syncthreads();

  // ---------------- Phase 7: top-K by rank (4 lanes/node) ----------------
  {
    const int n = tid >> 2, q = tid & 3;
    const float fn = rsf[n];
    int r = 0;
    for (int m = q * 64; m < q * 64 + 64; ++m) {
      const float fm = rsf[m];
      r += ((fm > fn) || (fm == fn && m < n)) ? 1 : 0;
    }
    r += __shfl_xor(r, 1); r += __shfl_xor(r, 2);
    if (q == 0 && r < KKEEP) kept[r] = n;   // unique rank -> deterministic
  }
  __syncthreads();

  // ---------------- Phase 8: in-neighbor bitmasks (incl self) ----------------
  Imask[tid] = 0ull;
  __syncthreads();
  if (tid < NPGL) atomicOr(&Imask[tid * 4 + (tid >> 6)], 1ull << (tid & 63));
#pragma unroll
  for (int i = 0; i < 2; ++i)
    atomicOr(&Imask[ed[i] * 4 + (es[i] >> 6)], 1ull << (es[i] & 63));
  __syncthreads();

  // ---------------- Phase 9: R[q] = union of I[m] over m in I[kept[q]]; conn ----------------
  if (tid < KKEEP * 4) {
    const int q = tid >> 2, w = tid & 3;
    const int kq = kept[q];
    unsigned long long acc = 0ull;
#pragma unroll
    for (int ww = 0; ww < 4; ++ww) {
      unsigned long long bits = Imask[kq * 4 + ww];
      while (bits) {
        const int m = (ww << 6) + __builtin_ctzll(bits);
        bits &= bits - 1;
        acc |= Imask[m * 4 + w];
      }
    }
    Rmask[q * 4 + w] = acc;
  }
  __syncthreads();
  if (tid < KKEEP * 2) conn[tid] = 0ull;
  __syncthreads();
  if (tid < KKEEP * 4) {
    const int p = tid >> 2, wb = tid & 3;
    const int kp = kept[p];
    const unsigned long long I0 = Imask[kp * 4 + 0], I1 = Imask[kp * 4 + 1],
                             I2 = Imask[kp * 4 + 2], I3 = Imask[kp * 4 + 3];
    unsigned long long bits = 0ull;
    for (int j = 0; j < 32; ++j) {
      const int q = wb * 32 + j;
      if (q == p) continue;
      const unsigned long long* R = &Rmask[q * 4];
      if ((I0 & R[0]) | (I1 & R[1]) | (I2 & R[2]) | (I3 & R[3]))
        bits |= 1ull << (q & 63);
    }
    atomicOr(&conn[p * 2 + (wb >> 1)], bits);
  }
  __syncthreads();

  // ---------------- Phase 10: deg2, d2, c[s] ----------------
  if (tid < KKEEP) {
    const int q = tid;
    const int w = q >> 6;
    const unsigned long long bq = 1ull << (q & 63);
    int deg = 1;
    for (int p = 0; p < KKEEP; ++p) deg += (conn[p * 2 + w] & bq) ? 1 : 0;
    d2A[q] = rsqrtf((float)deg);
  }
  __syncthreads();
  if (tid < KKEEP) {
    const int s = tid;
    float acc = d2A[s];
#pragma unroll
    for (int w = 0; w < 2; ++w) {
      unsigned long long bits = conn[s * 2 + w];
      while (bits) {
        const int d = (w << 6) + __builtin_ctzll(bits);
        bits &= bits - 1;
        acc += d2A[d];
      }
    }
    cA[s] = d2A[s] * acc * rsf[kept[s]] * (1.0f / (float)KKEEP);
  }
  __syncthreads();

  // ---------------- Phase 11: wsum (own 32 k), exchange, out ----------------
  {
    const int k = tid & 31, sblk = tid >> 5;   // 32 blocks of 4 kept nodes
    float p = 0.f;
#pragma unroll
    for (int j = 0; j < 4; ++j) {
      const int s = sblk * 4 + j;
      const int ks = kept[s];
      p += cA[s] * buf[swz8(ks, k >> 2) + (k & 3)];
    }
    esc[sblk * 32 + k] = p;
  }
  __syncthreads();
  if (tid < 32) {
    float s = 0.f;
#pragma unroll
    for (int b = 0; b < 32; ++b) s += esc[b * 32 + tid];
    wsum[F0 + tid] = s;
    datm[1280 + tid] = s;
  }
  pair_sync(flags, bid, 2);
  if (tid < 32) wsum[(F0 ^ 32) + tid] = datp[1280 + tid];
  __syncthreads();
  if (tid < 32) {
    const int f = F0 + tid;
    float o = b2[f];
    for (int k = 0; k < 64; ++k) o += wsum[k] * W2[k * 64 + f];
    out[(size_t)g * 64 + f] = o;
  }
}

extern "C" void kernel_launch(void* const* d_in, const int* in_sizes, int n_in,
                              void* d_out, int out_size, void* d_ws, size_t ws_size,
                              hipStream_t stream) {
  (void)n_in; (void)out_size; (void)ws_size;
  const float* x    = (const float*)d_in[0];
  const int*   ei   = (const int*)d_in[1];
  // d_in[2] = batch (contiguous equal graphs; unused)
  const float* W1   = (const float*)d_in[3];
  const float* b1   = (const float*)d_in[4];
  const float* linW = (const float*)d_in[5];
  const float* linb = (const float*)d_in[6];
  const float* attW = (const float*)d_in[7];
  const float* attb = (const float*)d_in[8];
  const float* le1W = (const float*)d_in[9];
  const float* le1b = (const float*)d_in[10];
  const float* le2W = (const float*)d_in[11];
  const float* le3W = (const float*)d_in[12];
  const float* le3b = (const float*)d_in[13];
  const float* W2   = (const float*)d_in[14];
  const float* b2   = (const float*)d_in[15];
  const int Etot = in_sizes[1] / 2;   // 524288
  const int nGraphs = 256;

  int* flags = (int*)d_ws;                       // 512*4 ints = 8KB
  float* dat = (float*)((char*)d_ws + 8192);     // 512 * WS_STRIDE floats

  hipMemsetAsync(d_ws, 0, 8192, stream);         // reset pair-sync flags

  asap_fused<<<dim3(nGraphs * 2), dim3(NTH), 0, stream>>>(
      x, ei, W1, b1, linW, linb, attW, attb, le1W, le1b, le2W, le3W, le3b,
      W2, b2, (float*)d_out, flags, dat, Etot);
}

// Round 5
// 59.337 us; speedup vs baseline: 8.2798x; 8.2798x over previous
//
#include <hip/hip_runtime.h>

#define NPGL 256     // nodes per graph
#define EPGL 2048    // edges per graph
#define HIDD 64
#define KKEEP 128
#define NTH 1024

// float offset of float4-chunk c (0..15) of row n in the swizzled LDS tile.
__device__ __forceinline__ int swz(int n, int c) {
  return (n << 6) + ((((c ^ n) ^ (n >> 4)) & 15) << 2);
}

__global__ void __launch_bounds__(NTH)
asap_fused(const float* __restrict__ x, const int* __restrict__ ei,
           const float* __restrict__ W1, const float* __restrict__ b1,
           const float* __restrict__ linW, const float* __restrict__ linb,
           const float* __restrict__ attW, const float* __restrict__ attb,
           const float* __restrict__ le1W, const float* __restrict__ le1b,
           const float* __restrict__ le2W,
           const float* __restrict__ le3W, const float* __restrict__ le3b,
           const float* __restrict__ W2, const float* __restrict__ b2,
           float* __restrict__ out, int Etot)
{
  const int g = blockIdx.x;
  const int tid = threadIdx.x;

  __shared__ __align__(16) float buf[NPGL * HIDD];   // 64KB: x -> h -> h1 -> xnew
  __shared__ __align__(16) float mskf[4096];         // 16KB: bitmask phase scratch
  __shared__ unsigned short csrc[EPGL];              // 4KB CSR src (by dst)
  __shared__ int rowst[NPGL + 1];
  __shared__ int cnt[NPGL];
  __shared__ float dinv_[NPGL];                      // later: c3 per node
  __shared__ float sA[NPGL], sB[NPGL];               // later: a, bb per node
  __shared__ float rsf[NPGL];                        // fitness
  __shared__ __align__(16) float esc[EPGL];          // 8KB: exp scores / partials
  __shared__ float u_[HIDD];
  __shared__ float wsum[HIDD];
  __shared__ int scanw[4];
  __shared__ float c0s;
  __shared__ int perm[NPGL];                         // degree-sorted dst order
  __shared__ int dhist[64];
  __shared__ int dcur[64];

  // aliases into mskf
  unsigned long long* Imask = (unsigned long long*)mskf;           // [256*4]
  unsigned long long* Rmask = ((unsigned long long*)mskf) + 1024;  // [128*4]
  unsigned long long* conn  = ((unsigned long long*)mskf) + 1536;  // [128*2]
  int*   kept = (int*)(mskf + 3584);                               // [128]
  float* d2A  = mskf + 3712;                                       // [128]
  float* cA   = mskf + 3840;                                       // [128]

  const int ebase = g * EPGL;
  const int nbase = g * NPGL;

  // ---------------- Phase 0: CSR build (by dst) + x staging ----------------
  if (tid < NPGL) cnt[tid] = 0;
  if (tid >= NTH - 64) dhist[tid - (NTH - 64)] = 0;
  __syncthreads();

  int es[2], ed[2];
#pragma unroll
  for (int i = 0; i < 2; ++i) {
    const int e = tid + i * NTH;
    es[i] = ei[ebase + e] - nbase;
    ed[i] = ei[Etot + ebase + e] - nbase;
    atomicAdd(&cnt[ed[i]], 1);
  }
  __syncthreads();

  int vscan = 0;
  if (tid < NPGL) {                 // wave-level inclusive scan over 256 counts
    vscan = cnt[tid];
#pragma unroll
    for (int off = 1; off < 64; off <<= 1) {
      const int up = __shfl_up(vscan, off, 64);
      if ((tid & 63) >= off) vscan += up;
    }
    if ((tid & 63) == 63) scanw[tid >> 6] = vscan;
  }
  __syncthreads();
  if (tid < NPGL) {
    int add = 0;
    const int w = tid >> 6;
    for (int ww = 0; ww < w; ++ww) add += scanw[ww];
    const int incl = vscan + add;
    rowst[tid + 1] = incl;
    cnt[tid] = incl - cnt[tid];     // exclusive scan = scatter cursor
    if (tid == 0) rowst[0] = 0;
  }
  __syncthreads();

#pragma unroll
  for (int i = 0; i < 2; ++i) {
    const int p = atomicAdd(&cnt[ed[i]], 1);
    csrc[p] = (unsigned short)es[i];
  }
  if (tid < NPGL) {
    const int len = rowst[tid + 1] - rowst[tid];
    dinv_[tid] = rsqrtf((float)len + 1.0f);       // conv1: +1 self loop
    atomicAdd(&dhist[len < 63 ? len : 63], 1);    // degree histogram
  }
  if (tid < HIDD) {                               // u = lin_W @ attW[:64]
    float a = 0.f;
    for (int f = 0; f < HIDD; ++f) a += linW[tid * HIDD + f] * attW[f];
    u_[tid] = a;
  }
  if (tid == 0) {
    float a = 0.f;
    for (int f = 0; f < HIDD; ++f) a += linb[f] * attW[f];
    c0s = a + attb[0];
  }
  // stage x -> buf (swizzled)
  {
    const float4* xg = (const float4*)(x + (size_t)nbase * HIDD);
#pragma unroll
    for (int ii = 0; ii < 4; ++ii) {
      const int i = tid + ii * NTH;
      const int r = i >> 4, c = i & 15;
      *(float4*)&buf[swz(r, c)] = xg[i];
    }
  }
  __syncthreads();

  // ---------------- Phase 1: h = x @ W1 (W1 via scalar loads) ----------------
  {
    const int wv = tid >> 6;                 // 0..15
    const int r  = ((wv & 3) << 6) + (tid & 63);   // row (wave-uniform group)
    const int fc = __builtin_amdgcn_readfirstlane(wv >> 2);  // 16-feature chunk
    const float* __restrict__ Wg = W1 + fc * 16;   // scalar base
    float4 acc[4];
#pragma unroll
    for (int c = 0; c < 4; ++c) acc[c] = make_float4(0.f, 0.f, 0.f, 0.f);
#pragma unroll
    for (int p = 0; p < 4; ++p) {
      float4 xa[4];
#pragma unroll
      for (int c = 0; c < 4; ++c) xa[c] = *(const float4*)&buf[swz(r, p * 4 + c)];
#pragma unroll
      for (int kk = 0; kk < 16; ++kk) {
        const int k = p * 16 + kk;
        const float xv = ((const float*)xa)[kk];
        const float* __restrict__ Wk = Wg + k * HIDD;  // uniform -> s_load
#pragma unroll
        for (int c = 0; c < 4; ++c) {
          const float4 w = *(const float4*)(Wk + c * 4);
          acc[c].x += xv * w.x; acc[c].y += xv * w.y;
          acc[c].z += xv * w.z; acc[c].w += xv * w.w;
        }
      }
    }
    __syncthreads();                // all x reads done before h overwrite
#pragma unroll
    for (int c = 0; c < 4; ++c) *(float4*)&buf[swz(r, fc * 4 + c)] = acc[c];
  }
  __syncthreads();

  // ---------------- degree-sort finalize: bin scan + perm scatter ----------------
  if (tid < 64) {
    const int v = dhist[tid];
    int s = v;
#pragma unroll
    for (int off = 1; off < 64; off <<= 1) {
      const int up = __shfl_up(s, off, 64);
      if (tid >= off) s += up;
    }
    dcur[tid] = s - v;              // exclusive prefix
  }
  __syncthreads();
  if (tid < NPGL) {
    const int len = rowst[tid + 1] - rowst[tid];
    const int b = len < 63 ? len : 63;
    perm[atomicAdd(&dcur[b], 1)] = tid;
  }
  __syncthreads();

  // ---------------- Phase 2: h1 = relu(GCN agg) (in-place, degree-sorted) ----------------
  {
    const int d = perm[tid >> 2], hh = tid & 3;    // chunks hh, hh+4, hh+8, hh+12
    const float dd = dinv_[d];
    const float sc_ = dd * dd;
    float4 acc[4];
#pragma unroll
    for (int j = 0; j < 4; ++j) {
      const int c = hh + 4 * j;
      const float4 hv = *(const float4*)&buf[swz(d, c)];
      const float4 bv = *(const float4*)&b1[4 * c];
      acc[j].x = hv.x * sc_ + bv.x; acc[j].y = hv.y * sc_ + bv.y;
      acc[j].z = hv.z * sc_ + bv.z; acc[j].w = hv.w * sc_ + bv.w;
    }
    const int s0 = rowst[d], s1 = rowst[d + 1];
    int it = s0;
    for (; it + 2 <= s1; it += 2) {
      const int sa_ = csrc[it], sb_ = csrc[it + 1];
      const float ca_ = dinv_[sa_] * dd, cb_ = dinv_[sb_] * dd;
#pragma unroll
      for (int j = 0; j < 4; ++j) {
        const float4 ha = *(const float4*)&buf[swz(sa_, hh + 4 * j)];
        const float4 hb = *(const float4*)&buf[swz(sb_, hh + 4 * j)];
        acc[j].x += ca_ * ha.x + cb_ * hb.x;
        acc[j].y += ca_ * ha.y + cb_ * hb.y;
        acc[j].z += ca_ * ha.z + cb_ * hb.z;
        acc[j].w += ca_ * ha.w + cb_ * hb.w;
      }
    }
    if (it < s1) {
      const int s = csrc[it];
      const float cf = dinv_[s] * dd;
#pragma unroll
      for (int j = 0; j < 4; ++j) {
        const float4 hv = *(const float4*)&buf[swz(s, hh + 4 * j)];
        acc[j].x += cf * hv.x; acc[j].y += cf * hv.y;
        acc[j].z += cf * hv.z; acc[j].w += cf * hv.w;
      }
    }
#pragma unroll
    for (int j = 0; j < 4; ++j) {
      acc[j].x = fmaxf(acc[j].x, 0.f); acc[j].y = fmaxf(acc[j].y, 0.f);
      acc[j].z = fmaxf(acc[j].z, 0.f); acc[j].w = fmaxf(acc[j].w, 0.f);
    }
    __syncthreads();
#pragma unroll
    for (int j = 0; j < 4; ++j) *(float4*)&buf[swz(d, hh + 4 * j)] = acc[j];
  }
  __syncthreads();

  // ---------------- Phase 3: sA (segment-max dot u), sB (degree-sorted) ----------------
  {
    const int d = perm[tid >> 2], hh = tid & 3;
    float4 mx[4];
    float sBp = 0.f;
#pragma unroll
    for (int j = 0; j < 4; ++j) {
      const int c = hh + 4 * j;
      const float4 hv = *(const float4*)&buf[swz(d, c)];
      mx[j] = hv;
      const float4 aw = *(const float4*)&attW[HIDD + 4 * c];
      sBp += hv.x * aw.x + hv.y * aw.y + hv.z * aw.z + hv.w * aw.w;
    }
    const int s0 = rowst[d], s1 = rowst[d + 1];
    int it = s0;
    for (; it + 2 <= s1; it += 2) {
      const int sa_ = csrc[it], sb_ = csrc[it + 1];
#pragma unroll
      for (int j = 0; j < 4; ++j) {
        const float4 ha = *(const float4*)&buf[swz(sa_, hh + 4 * j)];
        const float4 hb = *(const float4*)&buf[swz(sb_, hh + 4 * j)];
        mx[j].x = fmaxf(mx[j].x, fmaxf(ha.x, hb.x));
        mx[j].y = fmaxf(mx[j].y, fmaxf(ha.y, hb.y));
        mx[j].z = fmaxf(mx[j].z, fmaxf(ha.z, hb.z));
        mx[j].w = fmaxf(mx[j].w, fmaxf(ha.w, hb.w));
      }
    }
    if (it < s1) {
      const int s = csrc[it];
#pragma unroll
      for (int j = 0; j < 4; ++j) {
        const float4 hv = *(const float4*)&buf[swz(s, hh + 4 * j)];
        mx[j].x = fmaxf(mx[j].x, hv.x); mx[j].y = fmaxf(mx[j].y, hv.y);
        mx[j].z = fmaxf(mx[j].z, hv.z); mx[j].w = fmaxf(mx[j].w, hv.w);
      }
    }
    float sAp = 0.f;
#pragma unroll
    for (int j = 0; j < 4; ++j) {
      const float* uu = &u_[4 * (hh + 4 * j)];
      sAp += mx[j].x * uu[0] + mx[j].y * uu[1] + mx[j].z * uu[2] + mx[j].w * uu[3];
    }
    // deterministic quad combine: ((p0+p1)+(p2+p3))
    sAp += __shfl_xor(sAp, 1); sAp += __shfl_xor(sAp, 2);
    sBp += __shfl_xor(sBp, 1); sBp += __shfl_xor(sBp, 2);
    if (hh == 0) { sA[d] = c0s + sAp; sB[d] = sBp; }
  }
  __syncthreads();

  // ---------------- Phase 4+5 merged: softmax + xnew gather (same wave) ----------------
  {
    const int d = perm[tid >> 2], hh = tid & 3;
    const float sa = sA[d];
    const int s0 = rowst[d], s1 = rowst[d + 1];
    float scS = sa + sB[d];
    scS = scS >= 0.f ? scS : 0.2f * scS;
    float mxv = scS;
    for (int it = s0 + hh; it < s1; it += 4) {
      float sc = sa + sB[csrc[it]];
      sc = sc >= 0.f ? sc : 0.2f * sc;
      mxv = fmaxf(mxv, sc);
    }
    mxv = fmaxf(mxv, __shfl_xor(mxv, 1));
    mxv = fmaxf(mxv, __shfl_xor(mxv, 2));
    float sum = 0.f;
    for (int it = s0 + hh; it < s1; it += 4) {
      float sc = sa + sB[csrc[it]];
      sc = sc >= 0.f ? sc : 0.2f * sc;
      const float e = __expf(sc - mxv);
      esc[it] = e;
      sum += e;
    }
    sum += __shfl_xor(sum, 1); sum += __shfl_xor(sum, 2);
    const float esf = __expf(scS - mxv);
    const float rs = 1.0f / (esf + sum + 1e-16f);

    // xnew gather (esc produced by this wave's own lanes; lgkmcnt ordering)
    float4 acc[4];
#pragma unroll
    for (int j = 0; j < 4; ++j) {
      const float4 hv = *(const float4*)&buf[swz(d, hh + 4 * j)];
      acc[j].x = esf * hv.x; acc[j].y = esf * hv.y;
      acc[j].z = esf * hv.z; acc[j].w = esf * hv.w;
    }
    int it = s0;
    for (; it + 2 <= s1; it += 2) {
      const int sa_ = csrc[it], sb_ = csrc[it + 1];
      const float ea = esc[it], eb = esc[it + 1];
#pragma unroll
      for (int j = 0; j < 4; ++j) {
        const float4 ha = *(const float4*)&buf[swz(sa_, hh + 4 * j)];
        const float4 hb = *(const float4*)&buf[swz(sb_, hh + 4 * j)];
        acc[j].x += ea * ha.x + eb * hb.x;
        acc[j].y += ea * ha.y + eb * hb.y;
        acc[j].z += ea * ha.z + eb * hb.z;
        acc[j].w += ea * ha.w + eb * hb.w;
      }
    }
    if (it < s1) {
      const int s = csrc[it];
      const float e = esc[it];
#pragma unroll
      for (int j = 0; j < 4; ++j) {
        const float4 hv = *(const float4*)&buf[swz(s, hh + 4 * j)];
        acc[j].x += e * hv.x; acc[j].y += e * hv.y;
        acc[j].z += e * hv.z; acc[j].w += e * hv.w;
      }
    }
#pragma unroll
    for (int j = 0; j < 4; ++j) {
      acc[j].x *= rs; acc[j].y *= rs; acc[j].z *= rs; acc[j].w *= rs;
    }
    __syncthreads();
#pragma unroll
    for (int j = 0; j < 4; ++j) *(float4*)&buf[swz(d, hh + 4 * j)] = acc[j];
  }
  __syncthreads();

  // ---------------- Phase 6: LEConv fitness (4 lanes/node) ----------------
  {
    const int n = tid >> 2, q = tid & 3;
    float av = 0.f, bv = 0.f, cv = 0.f;
#pragma unroll
    for (int j = 0; j < 4; ++j) {
      const int c = q + 4 * j;
      const float4 v = *(const float4*)&buf[swz(n, c)];
      const int k = c * 4;
      av += v.x * le1W[k] + v.y * le1W[k + 1] + v.z * le1W[k + 2] + v.w * le1W[k + 3];
      bv += v.x * le2W[k] + v.y * le2W[k + 1] + v.z * le2W[k + 2] + v.w * le2W[k + 3];
      cv += v.x * le3W[k] + v.y * le3W[k + 1] + v.z * le3W[k + 2] + v.w * le3W[k + 3];
    }
    av += __shfl_xor(av, 1); av += __shfl_xor(av, 2);
    bv += __shfl_xor(bv, 1); bv += __shfl_xor(bv, 2);
    cv += __shfl_xor(cv, 1); cv += __shfl_xor(cv, 2);
    if (q == 0) {
      sA[n] = av + le1b[0];     // a
      sB[n] = bv;               // b2_
      dinv_[n] = cv + le3b[0];  // lin3 term
    }
  }
  __syncthreads();
  {
    const int d = perm[tid >> 2], q = tid & 3;
    const int s0 = rowst[d], s1 = rowst[d + 1];
    float fp = 0.f;
    for (int it = s0 + q; it < s1; it += 4) fp += sA[csrc[it]];
    fp += __shfl_xor(fp, 1); fp += __shfl_xor(fp, 2);
    if (q == 0) {
      float f = sA[d] + fp;                        // self-loop a + edge sum
      f -= (float)(s1 - s0 + 1) * sB[d];           // degF * b2_
      f += dinv_[d];
      float sg;
      if (f >= 0.f) sg = 1.f / (1.f + expf(-f));
      else { const float t = expf(f); sg = t / (1.f + t); }
      rsf[d] = sg;                                 // fitness
    }
  }
  __syncthreads();

  // ---------------- Phase 7: top-K by rank (4 lanes/node) ----------------
  {
    const int n = tid >> 2, q = tid & 3;
    const float fn = rsf[n];
    int r = 0;
    for (int m = q * 64; m < q * 64 + 64; ++m) {
      const float fm = rsf[m];
      r += ((fm > fn) || (fm == fn && m < n)) ? 1 : 0;
    }
    r += __shfl_xor(r, 1); r += __shfl_xor(r, 2);
    if (q == 0 && r < KKEEP) kept[r] = n;   // unique rank -> deterministic
  }
  __syncthreads();

  // ---------------- Phase 8: in-neighbor bitmasks (incl self) ----------------
  Imask[tid] = 0ull;
  __syncthreads();
  if (tid < NPGL) atomicOr(&Imask[tid * 4 + (tid >> 6)], 1ull << (tid & 63));
#pragma unroll
  for (int i = 0; i < 2; ++i)
    atomicOr(&Imask[ed[i] * 4 + (es[i] >> 6)], 1ull << (es[i] & 63));
  __syncthreads();

  // ---------------- Phase 9: R[q] = union of I[m] over m in I[kept[q]] ----------------
  if (tid < KKEEP * 4) {
    const int q = tid >> 2, w = tid & 3;
    const int kq = kept[q];
    unsigned long long acc = 0ull;
#pragma unroll
    for (int ww = 0; ww < 4; ++ww) {
      unsigned long long bits = Imask[kq * 4 + ww];
      while (bits) {
        const int m = (ww << 6) + __builtin_ctzll(bits);
        bits &= bits - 1;
        acc |= Imask[m * 4 + w];
      }
    }
    Rmask[q * 4 + w] = acc;
  }
  __syncthreads();
  if (tid < KKEEP * 2) conn[tid] = 0ull;
  __syncthreads();
  if (tid < KKEEP * 4) {
    const int p = tid >> 2, wb = tid & 3;
    const int kp = kept[p];
    const unsigned long long I0 = Imask[kp * 4 + 0], I1 = Imask[kp * 4 + 1],
                             I2 = Imask[kp * 4 + 2], I3 = Imask[kp * 4 + 3];
    unsigned long long bits = 0ull;
    for (int j = 0; j < 32; ++j) {
      const int q = wb * 32 + j;
      if (q == p) continue;
      const unsigned long long* R = &Rmask[q * 4];
      if ((I0 & R[0]) | (I1 & R[1]) | (I2 & R[2]) | (I3 & R[3]))
        bits |= 1ull << (q & 63);
    }
    atomicOr(&conn[p * 2 + (wb >> 1)], bits);
  }
  __syncthreads();

  // ---------------- Phase 10: deg2, d2, c[s] ----------------
  if (tid < KKEEP) {
    const int q = tid;
    const int w = q >> 6;
    const unsigned long long bq = 1ull << (q & 63);
    int deg = 1;
    for (int p = 0; p < KKEEP; ++p) deg += (conn[p * 2 + w] & bq) ? 1 : 0;
    d2A[q] = rsqrtf((float)deg);
  }
  __syncthreads();
  if (tid < KKEEP) {
    const int s = tid;
    float acc = d2A[s];
#pragma unroll
    for (int w = 0; w < 2; ++w) {
      unsigned long long bits = conn[s * 2 + w];
      while (bits) {
        const int d = (w << 6) + __builtin_ctzll(bits);
        bits &= bits - 1;
        acc += d2A[d];
      }
    }
    cA[s] = d2A[s] * acc * rsf[kept[s]] * (1.0f / (float)KKEEP);
  }
  __syncthreads();

  // ---------------- Phase 11: wsum[k] = sum_s cA[s]*xnew[kept[s],k]; out ----------------
  {
    const int f = tid & 63, blk = tid >> 6;   // 16 blocks of 8 kept nodes
    float p = 0.f;
    for (int j = 0; j < 8; ++j) {
      const int s = blk * 8 + j;
      const int ks = kept[s];
      const int off = (ks << 6) + (((((f >> 2) ^ ks) ^ (ks >> 4)) & 15) << 2) + (f & 3);
      p += cA[s] * buf[off];
    }
    esc[blk * 64 + f] = p;
  }
  __syncthreads();
  if (tid < HIDD) {
    float s = 0.f;
#pragma unroll
    for (int b = 0; b < 16; ++b) s += esc[b * 64 + tid];
    wsum[tid] = s;
  }
  __syncthreads();
  if (tid < HIDD) {
    float o = b2[tid];
    for (int k = 0; k < HIDD; ++k) o += wsum[k] * W2[k * HIDD + tid];
    out[(size_t)g * HIDD + tid] = o;
  }
}

extern "C" void kernel_launch(void* const* d_in, const int* in_sizes, int n_in,
                              void* d_out, int out_size, void* d_ws, size_t ws_size,
                              hipStream_t stream) {
  (void)n_in; (void)out_size; (void)d_ws; (void)ws_size;
  const float* x    = (const float*)d_in[0];
  const int*   ei   = (const int*)d_in[1];
  // d_in[2] = batch (contiguous equal graphs; unused)
  const float* W1   = (const float*)d_in[3];
  const float* b1   = (const float*)d_in[4];
  const float* linW = (const float*)d_in[5];
  const float* linb = (const float*)d_in[6];
  const float* attW = (const float*)d_in[7];
  const float* attb = (const float*)d_in[8];
  const float* le1W = (const float*)d_in[9];
  const float* le1b = (const float*)d_in[10];
  const float* le2W = (const float*)d_in[11];
  const float* le3W = (const float*)d_in[12];
  const float* le3b = (const float*)d_in[13];
  const float* W2   = (const float*)d_in[14];
  const float* b2   = (const float*)d_in[15];
  const int Etot = in_sizes[1] / 2;   // 524288
  const int nGraphs = 256;

  asap_fused<<<dim3(nGraphs), dim3(NTH), 0, stream>>>(
      x, ei, W1, b1, linW, linb, attW, attb, le1W, le1b, le2W, le3W, le3b,
      W2, b2, (float*)d_out, Etot);
}